// Round 7
// baseline (1008.588 us; speedup 1.0000x reference)
//
#include <hip/hip_runtime.h>
#include <hip/hip_bf16.h>
#include <math.h>

// Problem constants
#define NB   1024   // batch
#define NT   60     // time steps
#define NC   10     // in channels
#define NDM  256    // d_model
#define NH   16     // heads
#define NDH  16     // per-head value dim
#define NA   13     // num attention queries
#define NM   208    // NA*NH
#define NMO  128    // MLP out
#define WROW (NDM*NA)   // 3328 floats per weight row (16 chunks of 208)

// Workspace layout (floats)
#define OFF_WEFF  0
#define N_WEFF    (NH*14*WROW)                 // 745,472 (compact (hk,mi) rows)
#define OFF_BEFF  (OFF_WEFF + N_WEFF)
#define N_BEFF    (NM*NH*NA)                   // 43,264
#define OFF_ATT   (OFF_BEFF + N_BEFF)
#define N_ATT     (NM*NB*NDH)                  // 3,407,872

#define LDS_FENCE() __asm__ __volatile__("s_waitcnt lgkmcnt(0)" ::: "memory")

// ---------------- K0: weff3[hk][mi][chunk c][ak][d16], m = 13*hk+mi
__global__ void ltae_weff(const float* __restrict__ Q, const float* __restrict__ Wk,
                          const float* __restrict__ bk, float* __restrict__ weff3,
                          float* __restrict__ beff2) {
    int blk = blockIdx.x;            // hk*14 + mi
    int hk = blk / 14, mi = blk - hk*14;
    int m  = hk*13 + mi;
    int mc = m > 207 ? 207 : m;      // slot (15,13) is provably never read (rstar>=13 at mi=12)
    int d = threadIdx.x;
    float q0 = Q[mc*4+0], q1 = Q[mc*4+1], q2 = Q[mc*4+2], q3 = Q[mc*4+3];
    float outv[NA];
#pragma unroll
    for (int ak = 0; ak < NA; ++ak) {
        int e = (ak*16 + hk)*4;
        outv[ak] = q0*Wk[(size_t)(e+0)*NDM + d] + q1*Wk[(size_t)(e+1)*NDM + d]
                 + q2*Wk[(size_t)(e+2)*NDM + d] + q3*Wk[(size_t)(e+3)*NDM + d];
    }
    // chunked [ak][d16] layout: base + (c*13+ak)*16 + dl
    size_t base = (size_t)blk*WROW;
    int c = d >> 4, dl = d & 15;
#pragma unroll
    for (int ak = 0; ak < NA; ++ak) weff3[base + (size_t)(c*13 + ak)*16 + dl] = outv[ak];
    if (d < NA && m <= 207) {
        int e = (d*16 + hk)*4;
        beff2[(m*16 + hk)*NA + d] = q0*bk[e] + q1*bk[e+1] + q2*bk[e+2] + q3*bk[e+3];
    }
}

// ---------------- K2: fused conv+GN + scrambled attention; block = b, wave = hk
// LDS: Vt fp32 [256][66] + wbuf[16 hk][208] (weight chunk / x-stage / softmax buf)
#define VT_S   66
#define VT_F   (NDM*VT_S)            // 16,896 floats = 67,584 B
#define WB_F   (NH*208)              // 3,328 floats = 13,312 B
#define K2_LDS_BYTES ((VT_F + WB_F)*4)  // 80,896 B <= 81,920 -> 2 blocks/CU

#define FMA16(ACC, V, W0, W1, W2, W3) do { \
    ACC = fmaf(V[0],  W0.x, ACC); ACC = fmaf(V[1],  W0.y, ACC); \
    ACC = fmaf(V[2],  W0.z, ACC); ACC = fmaf(V[3],  W0.w, ACC); \
    ACC = fmaf(V[4],  W1.x, ACC); ACC = fmaf(V[5],  W1.y, ACC); \
    ACC = fmaf(V[6],  W1.z, ACC); ACC = fmaf(V[7],  W1.w, ACC); \
    ACC = fmaf(V[8],  W2.x, ACC); ACC = fmaf(V[9],  W2.y, ACC); \
    ACC = fmaf(V[10], W2.z, ACC); ACC = fmaf(V[11], W2.w, ACC); \
    ACC = fmaf(V[12], W3.x, ACC); ACC = fmaf(V[13], W3.y, ACC); \
    ACC = fmaf(V[14], W3.z, ACC); ACC = fmaf(V[15], W3.w, ACC); } while (0)

__launch_bounds__(1024, 8)
__global__ void ltae_fused(const float* __restrict__ x, const float* __restrict__ Wc,
                           const float* __restrict__ bc, const float* __restrict__ gnw,
                           const float* __restrict__ gnb, const float* __restrict__ weff3,
                           const float* __restrict__ beff2, float* __restrict__ attout) {
    extern __shared__ float smem[];
    float* Vt    = smem;
    float* wbufF = smem + VT_F;

    int b = blockIdx.x, tid = threadIdx.x;

    // ---- stage x[b] (600 floats) into wbuf region (dead until GEMM staging)
    float* xs = wbufF;
    if (tid < NT*NC) xs[tid] = x[(size_t)b*NT*NC + tid];
    __syncthreads();

    // ---- conv 1x1 + GroupNorm(16 groups over 16ch x 60t), write Vt fp32 [d][t]
    {
        int d = tid >> 2, q = tid & 3;   // wave w covers d in [16w,16w+16) = GN group w
        float wc[NC];
#pragma unroll
        for (int c = 0; c < NC; ++c) wc[c] = Wc[d*NC + c];
        float bcv = bc[d];
        float h[15];
        float s1 = 0.f, s2 = 0.f;
#pragma unroll
        for (int k = 0; k < 15; ++k) {
            int t = 15*q + k;
            float a = bcv;
#pragma unroll
            for (int c = 0; c < NC; ++c) a = fmaf(xs[t*NC + c], wc[c], a);
            h[k] = a; s1 += a; s2 += a*a;
        }
#pragma unroll
        for (int off = 1; off < 64; off <<= 1) {
            s1 += __shfl_xor(s1, off);
            s2 += __shfl_xor(s2, off);
        }
        float mean = s1 * (1.f/960.f);
        float var  = s2 * (1.f/960.f) - mean*mean;
        float rstd = rsqrtf(var + 1e-5f);
        float g = gnw[d], bb = gnb[d];
#pragma unroll
        for (int k = 0; k < 15; ++k) {
            int t = 15*q + k;
            Vt[d*VT_S + t] = (h[k]-mean)*rstd*g + bb;
        }
        if (q == 0) {
#pragma unroll
            for (int t = NT; t < VT_S; ++t) Vt[d*VT_S + t] = 0.f;
        }
    }
    __syncthreads();

    // ---- per-wave attention: wave = hk, lane = tk
    int wid = tid >> 6, lane = tid & 63;
    int hk = wid;
    int tk = lane;
    int mi    = (13*b) >> 10;                        // block-uniform (exact)
    int rstar = ((mi+1) << 10) - 13*b;               // block-uniform; switch iff <13
    int hb13  = (hk*1024 + b)*13;

    float* wl = wbufF + hk*208;                      // my wave's staging slot
    bool ld = (lane < 52);

    float acc[13];
#pragma unroll
    for (int j = 0; j < 13; ++j) acc[j] = 0.f;

    // ---- pass A: row (hk, mi); 16 chunks of 16 d; vector-load + ds_write staging,
    // software-prefetched one chunk ahead (vmcnt in-order => partial waits possible);
    // weight reads are uniform-address aligned b128 = LDS broadcast, conflict-free.
    {
        const float* wrow = weff3 + (size_t)(hk*14 + mi)*WROW;
        float4 wreg;
        if (ld) wreg = *(const float4*)(wrow + lane*4);
#pragma unroll 1
        for (int c = 0; c < 16; ++c) {
            int cn = (c < 15) ? c+1 : 15;
            float4 wnxt;
            if (ld) wnxt = *(const float4*)(wrow + cn*208 + lane*4);
            if (ld) *(float4*)(wl + lane*4) = wreg;   // ds_write_b128 (same-wave in-order)
            LDS_FENCE();
            float v[16];
#pragma unroll
            for (int dd = 0; dd < 16; ++dd) v[dd] = Vt[(c*16+dd)*VT_S + tk];
#pragma unroll
            for (int ak = 0; ak < 13; ++ak) {
                const float* wp = wl + ak*16;
                float4 w0 = *(const float4*)(wp);
                float4 w1 = *(const float4*)(wp+4);
                float4 w2 = *(const float4*)(wp+8);
                float4 w3 = *(const float4*)(wp+12);
                FMA16(acc[ak], v, w0, w1, w2, w3);
            }
            wreg = wnxt;
        }
    }

    // ---- pass B (rare, block-uniform condition): row (hk, mi+1).
    // Lanes fully past the switch recompute in place (direct global reads;
    // ~1.2% of blocks), the single straddling lane bounces pass-A acc via LDS.
    if (rstar < 13) {
        int ustar = 60*rstar;            // u >= ustar uses variant mi+1
        int tstar = ustar / 13;          // straddling tk
        if (tk == tstar) {
#pragma unroll
            for (int j = 0; j < 13; ++j) wl[j] = acc[j];
        }
        LDS_FENCE();
        const float4* wr4 = (const float4*)(weff3 + (size_t)(hk*14 + mi + 1)*WROW);
        if (tk >= tstar) {
#pragma unroll
            for (int j = 0; j < 13; ++j) acc[j] = 0.f;
#pragma unroll 1
            for (int c = 0; c < 16; ++c) {
                float v[16];
#pragma unroll
                for (int dd = 0; dd < 16; ++dd) v[dd] = Vt[(c*16+dd)*VT_S + tk];
#pragma unroll
                for (int ak = 0; ak < 13; ++ak) {
                    float4 w0 = wr4[(c*13+ak)*4+0];
                    float4 w1 = wr4[(c*13+ak)*4+1];
                    float4 w2 = wr4[(c*13+ak)*4+2];
                    float4 w3 = wr4[(c*13+ak)*4+3];
                    FMA16(acc[ak], v, w0, w1, w2, w3);
                }
            }
        }
        if (tk == tstar) {
#pragma unroll
            for (int j = 0; j < 13; ++j)
                if (13*tk + j < ustar) acc[j] = wl[j];
        }
    }

    // ---- phased softmax + AV (5 u-ranges over wave-private myC = wl slot)
    float* myC = wl;
    int dh = lane >> 2, cc = lane & 3;
    const float* vrow = Vt + (hk*16 + dh)*VT_S;
    float vreg[15];
#pragma unroll
    for (int j = 0; j < 15; ++j) vreg[j] = vrow[cc + 4*j];

    const int ULO[5] = {0, 180, 360, 540, 720};
    const int RLO[5] = {0, 3, 6, 9, 12};
    const int RHI[5] = {3, 6, 9, 12, 13};
#pragma unroll 1
    for (int p = 0; p < 5; ++p) {
        int ulo = ULO[p];
        int uhi = (p == 4) ? 780 : ulo + 180;
        if (tk < NT) {
#pragma unroll
            for (int j = 0; j < 13; ++j) {
                int u = 13*tk + j;
                if (u >= ulo && u < uhi) myC[u - ulo] = acc[j];
            }
        }
        LDS_FENCE();
        for (int r = RLO[p]; r < RHI[p]; ++r) {
            int n = hb13 + r;
            int m = n >> 10;                         // exact variant for this row
            int brow = (m*16 + hk)*13;
            float logit = -1e30f;
            if (lane < NT) {
                int u  = r*60 + lane;
                int ak = u % 13;
                logit = (myC[u - ulo] + beff2[brow + ak]) * 0.5f;
            }
            float mx = logit;
#pragma unroll
            for (int off = 32; off; off >>= 1) mx = fmaxf(mx, __shfl_xor(mx, off));
            float e = (lane < NT) ? __expf(logit - mx) : 0.f;
            float s = e;
#pragma unroll
            for (int off = 32; off; off >>= 1) s += __shfl_xor(s, off);
            float attn = e / s;
            if (lane < NT) myC[r*60 - ulo + lane] = attn;  // same-wave in-order LDS
            LDS_FENCE();
            float a = 0.f;
#pragma unroll
            for (int j = 0; j < 15; ++j)
                a = fmaf(myC[r*60 - ulo + cc + 4*j], vreg[j], a);
            a += __shfl_xor(a, 1);
            a += __shfl_xor(a, 2);
            if (cc == 0) attout[(size_t)n*NDH + dh] = a;
        }
    }
}

// ---------------- K3: MLP + BN(eval) + ReLU + GroupNorm(16,128); 8 rows/block
__launch_bounds__(1024)
__global__ void ltae_mlp(const float* __restrict__ attout, const float* __restrict__ W1,
                         const float* __restrict__ b1, const float* __restrict__ bnw,
                         const float* __restrict__ bnb, const float* __restrict__ bnrm,
                         const float* __restrict__ bnrv, const float* __restrict__ gow,
                         const float* __restrict__ gob, float* __restrict__ out) {
    __shared__ float f[8][NDM];
    int tid = threadIdx.x;
    int sl  = tid >> 7;          // 0..7 row slot
    int j   = tid & 127;
    int sid = (blockIdx.x << 3) + sl;   // sid = a2*1024 + b2
    int a2  = sid >> 10, b2 = sid & 1023;
    for (int k = tid; k < 8*NDM; k += 1024) {
        int s = k >> 8, c = k & 255;
        int sid2 = (blockIdx.x << 3) + s;
        int aa = sid2 >> 10, bb = sid2 & 1023;
        int h2 = c >> 4, dhh = c & 15;
        f[s][c] = attout[((size_t)((aa*16 + h2)*1024 + bb))*NDH + dhh];
    }
    __syncthreads();
    const float* fr = f[sl];
    const float* w  = &W1[(size_t)j*NDM];
    float acc = b1[j];
    for (int c = 0; c < NDM; c += 4) {
        float4 wv = *(const float4*)&w[c];
        acc += wv.x*fr[c] + wv.y*fr[c+1] + wv.z*fr[c+2] + wv.w*fr[c+3];
    }
    float y = (acc - bnrm[j]) * rsqrtf(bnrv[j] + 1e-5f) * bnw[j] + bnb[j];
    y = fmaxf(y, 0.f);
    float s1 = y, s2 = y*y;
#pragma unroll
    for (int off = 1; off < 8; off <<= 1) {
        s1 += __shfl_xor(s1, off);
        s2 += __shfl_xor(s2, off);
    }
    float mean = s1 * 0.125f;
    float var  = s2 * 0.125f - mean*mean;
    float o = (y - mean) * rsqrtf(var + 1e-5f) * gow[j] + gob[j];
    out[((size_t)b2*NA + a2)*NMO + j] = o;
}

extern "C" void kernel_launch(void* const* d_in, const int* in_sizes, int n_in,
                              void* d_out, int out_size, void* d_ws, size_t ws_size,
                              hipStream_t stream) {
    const float* x    = (const float*)d_in[0];
    const float* Wc   = (const float*)d_in[1];
    const float* bc   = (const float*)d_in[2];
    const float* gnw  = (const float*)d_in[3];
    const float* gnb  = (const float*)d_in[4];
    const float* Q    = (const float*)d_in[5];
    const float* Wk   = (const float*)d_in[6];
    const float* bk   = (const float*)d_in[7];
    const float* W1   = (const float*)d_in[8];
    const float* b1   = (const float*)d_in[9];
    const float* bnw  = (const float*)d_in[10];
    const float* bnb  = (const float*)d_in[11];
    const float* bnrm = (const float*)d_in[12];
    const float* bnrv = (const float*)d_in[13];
    const float* gow  = (const float*)d_in[14];
    const float* gob  = (const float*)d_in[15];

    float* ws     = (float*)d_ws;
    float* weff3  = ws + OFF_WEFF;
    float* beff2  = ws + OFF_BEFF;
    float* attout = ws + OFF_ATT;
    float* outp   = (float*)d_out;

    hipLaunchKernelGGL(ltae_weff, dim3(NH*14), dim3(256), 0, stream, Q, Wk, bk, weff3, beff2);
    hipFuncSetAttribute((const void*)ltae_fused,
                        hipFuncAttributeMaxDynamicSharedMemorySize, K2_LDS_BYTES);
    hipLaunchKernelGGL(ltae_fused, dim3(NB), dim3(1024), K2_LDS_BYTES, stream,
                       x, Wc, bc, gnw, gnb, weff3, beff2, attout);
    hipLaunchKernelGGL(ltae_mlp, dim3(NA*NB/8), dim3(1024), 0, stream,
                       attout, W1, b1, bnw, bnb, bnrm, bnrv, gow, gob, outp);
}

// Round 8
// 499.194 us; speedup vs baseline: 2.0204x; 2.0204x over previous
//
#include <hip/hip_runtime.h>
#include <hip/hip_bf16.h>
#include <math.h>

// Problem constants
#define NB   1024   // batch
#define NT   60     // time steps
#define NC   10     // in channels
#define NDM  256    // d_model
#define NH   16     // heads
#define NDH  16     // per-head value dim
#define NA   13     // num attention queries
#define NM   208    // NA*NH
#define NMO  128    // MLP out

// weff4 row: 128 groups x 32 floats; group g covers d=2g (slots 0..12) and
// d=2g+1 (slots 16..28); slots 13-15/29-31 are pad (never read).
#define WROW4 4096

// Workspace layout (floats)
#define OFF_WEFF  0
#define N_WEFF    (NH*14*WROW4)                // 917,504
#define OFF_BEFF  (OFF_WEFF + N_WEFF)
#define N_BEFF    (NM*NH*NA)                   // 43,264
#define OFF_VGT   (OFF_BEFF + N_BEFF)
#define N_VGT     (NB*NDM*64)                  // 16,777,216 (v transposed [b][d][64])
#define OFF_ATT   (OFF_VGT + N_VGT)
#define N_ATT     (NM*NB*NDH)                  // 3,407,872   (total 84.6 MB)

#define LDS_FENCE() __asm__ __volatile__("s_waitcnt lgkmcnt(0)" ::: "memory")

typedef __attribute__((ext_vector_type(16))) float f16v;

// ---------------- K0: weff4[hk][mi][g][slot], m = 13*hk+mi
__global__ void ltae_weff(const float* __restrict__ Q, const float* __restrict__ Wk,
                          const float* __restrict__ bk, float* __restrict__ weff4,
                          float* __restrict__ beff2) {
    int blk = blockIdx.x;            // hk*14 + mi
    int hk = blk / 14, mi = blk - hk*14;
    int m  = hk*13 + mi;
    int mc = m > 207 ? 207 : m;      // slot (15,13) provably never read
    int d = threadIdx.x;
    float q0 = Q[mc*4+0], q1 = Q[mc*4+1], q2 = Q[mc*4+2], q3 = Q[mc*4+3];
    size_t base = (size_t)blk*WROW4 + (size_t)(d >> 1)*32 + (d & 1)*16;
#pragma unroll
    for (int ak = 0; ak < NA; ++ak) {
        int e = (ak*16 + hk)*4;
        float w = q0*Wk[(size_t)(e+0)*NDM + d] + q1*Wk[(size_t)(e+1)*NDM + d]
                + q2*Wk[(size_t)(e+2)*NDM + d] + q3*Wk[(size_t)(e+3)*NDM + d];
        weff4[base + ak] = w;
    }
    // zero pads so s_load reads defined memory
    if ((d & 1) == 0) { weff4[base+13]=0.f; weff4[base+14]=0.f; weff4[base+15]=0.f; }
    else              { weff4[base+13]=0.f; weff4[base+14]=0.f; weff4[base+15]=0.f; }
    if (d < NA && m <= 207) {
        int e = (d*16 + hk)*4;
        beff2[(m*16 + hk)*NA + d] = q0*bk[e] + q1*bk[e+1] + q2*bk[e+2] + q3*bk[e+3];
    }
}

// ---------------- K1: conv 1x1 + GroupNorm -> vgT[b][d][64] (t-padded, coalesced)
// LDS: Vt[256][66] + xs[600]  = 69,984 B -> 2 blocks/CU
#define VT_S 66
#define K1_LDS_BYTES ((NDM*VT_S + NT*NC)*4)

__launch_bounds__(1024, 8)
__global__ void ltae_convgn(const float* __restrict__ x, const float* __restrict__ Wc,
                            const float* __restrict__ bc, const float* __restrict__ gnw,
                            const float* __restrict__ gnb, float* __restrict__ vgT) {
    extern __shared__ float smem[];
    float* Vt = smem;
    float* xs = smem + NDM*VT_S;
    int b = blockIdx.x, tid = threadIdx.x;
    if (tid < NT*NC) xs[tid] = x[(size_t)b*NT*NC + tid];
    __syncthreads();
    {
        int d = tid >> 2, q = tid & 3;   // wave = 16 d = one GN group
        float wc[NC];
#pragma unroll
        for (int c = 0; c < NC; ++c) wc[c] = Wc[d*NC + c];
        float bcv = bc[d];
        float h[15];
        float s1 = 0.f, s2 = 0.f;
#pragma unroll
        for (int k = 0; k < 15; ++k) {
            int t = 15*q + k;
            float a = bcv;
#pragma unroll
            for (int c = 0; c < NC; ++c) a = fmaf(xs[t*NC + c], wc[c], a);
            h[k] = a; s1 += a; s2 += a*a;
        }
#pragma unroll
        for (int off = 1; off < 64; off <<= 1) {
            s1 += __shfl_xor(s1, off);
            s2 += __shfl_xor(s2, off);
        }
        float mean = s1 * (1.f/960.f);
        float var  = s2 * (1.f/960.f) - mean*mean;
        float rstd = rsqrtf(var + 1e-5f);
        float g = gnw[d], bb = gnb[d];
#pragma unroll
        for (int k = 0; k < 15; ++k)
            Vt[d*VT_S + 15*q + k] = (h[k]-mean)*rstd*g + bb;
    }
    __syncthreads();
    // coalesced transpose-out: [d][64] rows, zero pad t>=60
    float* vb = vgT + (size_t)b*NDM*64;
    for (int i = tid; i < NDM*64; i += 1024) {
        int d = i >> 6, t = i & 63;
        vb[i] = (t < NT) ? Vt[d*VT_S + t] : 0.f;
    }
}

// ---------------- K2: scrambled attention; block = b, wave = hk
// GEMM: weights via s_load (SGPR, lgkmcnt), v via global_load (vmcnt) —
// separate counter domains so both prefetch streams pipeline independently.
// LDS only for softmax buffers: wbuf[16][192] = 12,288 B.
__launch_bounds__(1024, 8)
__global__ void ltae_attn(const float* __restrict__ vgT, const float* __restrict__ weff4,
                          const float* __restrict__ beff2, float* __restrict__ attout) {
    __shared__ float wbuf[NH*192];
    int b = blockIdx.x, tid = threadIdx.x;
    int wid = tid >> 6, lane = tid & 63;
    int hk = __builtin_amdgcn_readfirstlane(wid);   // uniform -> scalar weight path
    int tk = lane;
    int mi    = (13*b) >> 10;                        // block-uniform
    int rstar = ((mi+1) << 10) - 13*b;               // switch iff <13
    int hb13  = (hk*1024 + b)*13;
    const float* __restrict__ vb = vgT + (size_t)b*NDM*64;

    float acc[13];
#pragma unroll
    for (int j = 0; j < 13; ++j) acc[j] = 0.f;

    // ---- pass A: row (hk, mi), 128 d-pair groups, dbuf prefetch (SGPR + VMEM)
    {
        const f16v* __restrict__ wr = (const f16v*)(weff4 + (size_t)(hk*14 + mi)*WROW4);
        f16v wA = wr[0], wB = wr[1];
        float v0 = vb[tk], v1 = vb[64 + tk];
#pragma unroll 1
        for (int g = 0; g < 128; ++g) {
            int gn = (g < 127) ? g+1 : 127;
            f16v nA = wr[2*gn], nB = wr[2*gn+1];
            float n0 = vb[(2*gn)*64 + tk];
            float n1 = vb[(2*gn+1)*64 + tk];
#pragma unroll
            for (int ak = 0; ak < 13; ++ak) acc[ak] = fmaf(v0, wA[ak], acc[ak]);
#pragma unroll
            for (int ak = 0; ak < 13; ++ak) acc[ak] = fmaf(v1, wB[ak], acc[ak]);
            wA = nA; wB = nB; v0 = n0; v1 = n1;
        }
    }

    // ---- pass B (rare, block-uniform): row (hk, mi+1); straddling lane bounces via LDS
    if (rstar < 13) {
        int ustar = 60*rstar;
        int tstar = ustar / 13;
        float* wl = wbuf + hk*192;
        if (tk == tstar) {
#pragma unroll
            for (int j = 0; j < 13; ++j) wl[j] = acc[j];
        }
        LDS_FENCE();
        {
            const f16v* __restrict__ wr = (const f16v*)(weff4 + (size_t)(hk*14 + mi + 1)*WROW4);
            bool redo = (tk >= tstar);
            float accB[13];
#pragma unroll
            for (int j = 0; j < 13; ++j) accB[j] = 0.f;
            f16v wA = wr[0], wB = wr[1];
            float v0 = vb[tk], v1 = vb[64 + tk];
#pragma unroll 1
            for (int g = 0; g < 128; ++g) {
                int gn = (g < 127) ? g+1 : 127;
                f16v nA = wr[2*gn], nB = wr[2*gn+1];
                float n0 = vb[(2*gn)*64 + tk];
                float n1 = vb[(2*gn+1)*64 + tk];
#pragma unroll
                for (int ak = 0; ak < 13; ++ak) accB[ak] = fmaf(v0, wA[ak], accB[ak]);
#pragma unroll
                for (int ak = 0; ak < 13; ++ak) accB[ak] = fmaf(v1, wB[ak], accB[ak]);
                wA = nA; wB = nB; v0 = n0; v1 = n1;
            }
            if (redo) {
#pragma unroll
                for (int j = 0; j < 13; ++j) acc[j] = accB[j];
            }
        }
        if (tk == tstar) {
#pragma unroll
            for (int j = 0; j < 13; ++j)
                if (13*tk + j < ustar) acc[j] = wl[j];
        }
    }

    // ---- phased softmax + AV (5 u-ranges over wave-private 192-float slot)
    float* myC = wbuf + hk*192;
    int dh = lane >> 2, cc = lane & 3;
    float vreg[15];
#pragma unroll
    for (int j = 0; j < 15; ++j) vreg[j] = vb[(hk*16 + dh)*64 + cc + 4*j];

    const int ULO[5] = {0, 180, 360, 540, 720};
    const int RLO[5] = {0, 3, 6, 9, 12};
    const int RHI[5] = {3, 6, 9, 12, 13};
#pragma unroll 1
    for (int p = 0; p < 5; ++p) {
        int ulo = ULO[p];
        int uhi = (p == 4) ? 780 : ulo + 180;
        if (tk < NT) {
#pragma unroll
            for (int j = 0; j < 13; ++j) {
                int u = 13*tk + j;
                if (u >= ulo && u < uhi) myC[u - ulo] = acc[j];
            }
        }
        LDS_FENCE();
        for (int r = RLO[p]; r < RHI[p]; ++r) {
            int n = hb13 + r;
            int m = n >> 10;                         // exact variant for this row
            int brow = (m*16 + hk)*13;
            float logit = -1e30f;
            if (lane < NT) {
                int u  = r*60 + lane;
                int ak = u % 13;
                logit = (myC[u - ulo] + beff2[brow + ak]) * 0.5f;
            }
            float mx = logit;
#pragma unroll
            for (int off = 32; off; off >>= 1) mx = fmaxf(mx, __shfl_xor(mx, off));
            float e = (lane < NT) ? __expf(logit - mx) : 0.f;
            float s = e;
#pragma unroll
            for (int off = 32; off; off >>= 1) s += __shfl_xor(s, off);
            float attn = e / s;
            if (lane < NT) myC[r*60 - ulo + lane] = attn;  // same-wave in-order LDS
            LDS_FENCE();
            float a = 0.f;
#pragma unroll
            for (int j = 0; j < 15; ++j)
                a = fmaf(myC[r*60 - ulo + cc + 4*j], vreg[j], a);
            a += __shfl_xor(a, 1);
            a += __shfl_xor(a, 2);
            if (cc == 0) attout[(size_t)n*NDH + dh] = a;
        }
    }
}

// ---------------- K3: MLP + BN(eval) + ReLU + GroupNorm(16,128); 8 rows/block
__launch_bounds__(1024)
__global__ void ltae_mlp(const float* __restrict__ attout, const float* __restrict__ W1,
                         const float* __restrict__ b1, const float* __restrict__ bnw,
                         const float* __restrict__ bnb, const float* __restrict__ bnrm,
                         const float* __restrict__ bnrv, const float* __restrict__ gow,
                         const float* __restrict__ gob, float* __restrict__ out) {
    __shared__ float f[8][NDM];
    int tid = threadIdx.x;
    int sl  = tid >> 7;          // 0..7 row slot
    int j   = tid & 127;
    int sid = (blockIdx.x << 3) + sl;   // sid = a2*1024 + b2
    int a2  = sid >> 10, b2 = sid & 1023;
    for (int k = tid; k < 8*NDM; k += 1024) {
        int s = k >> 8, c = k & 255;
        int sid2 = (blockIdx.x << 3) + s;
        int aa = sid2 >> 10, bb = sid2 & 1023;
        int h2 = c >> 4, dhh = c & 15;
        f[s][c] = attout[((size_t)((aa*16 + h2)*1024 + bb))*NDH + dhh];
    }
    __syncthreads();
    const float* fr = f[sl];
    const float* w  = &W1[(size_t)j*NDM];
    float acc = b1[j];
    for (int c = 0; c < NDM; c += 4) {
        float4 wv = *(const float4*)&w[c];
        acc += wv.x*fr[c] + wv.y*fr[c+1] + wv.z*fr[c+2] + wv.w*fr[c+3];
    }
    float y = (acc - bnrm[j]) * rsqrtf(bnrv[j] + 1e-5f) * bnw[j] + bnb[j];
    y = fmaxf(y, 0.f);
    float s1 = y, s2 = y*y;
#pragma unroll
    for (int off = 1; off < 8; off <<= 1) {
        s1 += __shfl_xor(s1, off);
        s2 += __shfl_xor(s2, off);
    }
    float mean = s1 * 0.125f;
    float var  = s2 * 0.125f - mean*mean;
    float o = (y - mean) * rsqrtf(var + 1e-5f) * gow[j] + gob[j];
    out[((size_t)b2*NA + a2)*NMO + j] = o;
}

extern "C" void kernel_launch(void* const* d_in, const int* in_sizes, int n_in,
                              void* d_out, int out_size, void* d_ws, size_t ws_size,
                              hipStream_t stream) {
    const float* x    = (const float*)d_in[0];
    const float* Wc   = (const float*)d_in[1];
    const float* bc   = (const float*)d_in[2];
    const float* gnw  = (const float*)d_in[3];
    const float* gnb  = (const float*)d_in[4];
    const float* Q    = (const float*)d_in[5];
    const float* Wk   = (const float*)d_in[6];
    const float* bk   = (const float*)d_in[7];
    const float* W1   = (const float*)d_in[8];
    const float* b1   = (const float*)d_in[9];
    const float* bnw  = (const float*)d_in[10];
    const float* bnb  = (const float*)d_in[11];
    const float* bnrm = (const float*)d_in[12];
    const float* bnrv = (const float*)d_in[13];
    const float* gow  = (const float*)d_in[14];
    const float* gob  = (const float*)d_in[15];

    float* ws     = (float*)d_ws;
    float* weff4  = ws + OFF_WEFF;
    float* beff2  = ws + OFF_BEFF;
    float* vgT    = ws + OFF_VGT;
    float* attout = ws + OFF_ATT;
    float* outp   = (float*)d_out;

    hipLaunchKernelGGL(ltae_weff, dim3(NH*14), dim3(256), 0, stream, Q, Wk, bk, weff4, beff2);
    hipFuncSetAttribute((const void*)ltae_convgn,
                        hipFuncAttributeMaxDynamicSharedMemorySize, K1_LDS_BYTES);
    hipLaunchKernelGGL(ltae_convgn, dim3(NB), dim3(1024), K1_LDS_BYTES, stream,
                       x, Wc, bc, gnw, gnb, vgT);
    hipLaunchKernelGGL(ltae_attn, dim3(NB), dim3(1024), 0, stream,
                       vgT, weff4, beff2, attout);
    hipLaunchKernelGGL(ltae_mlp, dim3(NA*NB/8), dim3(1024), 0, stream,
                       attout, W1, b1, bnw, bnb, bnrm, bnrv, gow, gob, outp);
}